// Round 6
// baseline (302.008 us; speedup 1.0000x reference)
//
#include <hip/hip_runtime.h>

// ---------- types ----------
typedef __attribute__((ext_vector_type(8))) __bf16 bf16x8;
typedef __attribute__((ext_vector_type(4))) float f32x4;
typedef __attribute__((ext_vector_type(8))) unsigned short u16x8;

__device__ __forceinline__ unsigned short f2b(float f) {
    union { float f; unsigned u; } v; v.f = f;
    unsigned r = v.u + 0x7FFFu + ((v.u >> 16) & 1u);   // RNE
    return (unsigned short)(r >> 16);
}

// m201 st_16x32 swizzle on 64B rows: flips byte-bit5 with row-bit3.
__device__ __forceinline__ unsigned swz(int row, int s) {
    return (unsigned)((row * 64 + s * 16) ^ ((row & 8) << 2));
}

#define GLDS(g, l) __builtin_amdgcn_global_load_lds(                        \
    (const __attribute__((address_space(1))) void*)(g),                     \
    (__attribute__((address_space(3))) void*)(l), 16, 0, 0)

// ---------- W [K][N=512] f32 -> pre-tiled + pre-swizzled bf16 image ----------
__global__ __launch_bounds__(256) void convw_pre_kernel(const float* __restrict__ W,
                                                        char* __restrict__ out, int K) {
    int t = blockIdx.x * 256 + threadIdx.x;
    if (t >= K * 512) return;
    int k = t >> 9, n = t & 511;
    int cb = n >> 8, r = n & 255, tt = k >> 5, s = (k & 31) >> 3, e = k & 7;
    size_t off = ((size_t)cb * (K >> 5) + tt) * 16384 + swz(r, s) + e * 2;
    *(unsigned short*)(out + off) = f2b(W[t]);
}

// ---------- CSR build (by dst) ----------
__global__ __launch_bounds__(256) void count_kernel(const int* __restrict__ dst,
                                                    int* __restrict__ counts, int E) {
    int e = blockIdx.x * 256 + threadIdx.x;
    if (e < E) atomicAdd(&counts[dst[e]], 1);
}

__global__ __launch_bounds__(1024) void scan_kernel(const int* __restrict__ counts,
                                                    int* __restrict__ offs, int N) {
    __shared__ int wsum[16], wpre[16];
    const int CH = 20;
    int tid = threadIdx.x, lane = tid & 63, wv = tid >> 6;
    int base = tid * CH;
    int s = 0;
    for (int i = 0; i < CH; i++) { int idx = base + i; s += (idx < N) ? counts[idx] : 0; }
    int run = s;
#pragma unroll
    for (int o = 1; o < 64; o <<= 1) { int v = __shfl_up(run, o, 64); if (lane >= o) run += v; }
    if (lane == 63) wsum[wv] = run;
    __syncthreads();
    if (tid == 0) { int acc = 0; for (int w = 0; w < 16; w++) { wpre[w] = acc; acc += wsum[w]; } }
    __syncthreads();
    int pre = wpre[wv] + (run - s);
    for (int i = 0; i < CH; i++) {
        int idx = base + i;
        if (idx <= N) offs[idx] = pre;
        pre += (idx < N) ? counts[idx] : 0;
    }
}

__global__ __launch_bounds__(256) void bucket_kernel(const int* __restrict__ src,
                                                     const int* __restrict__ dst,
                                                     const int* __restrict__ offs,
                                                     int* __restrict__ cursor,
                                                     int* __restrict__ eids, int E) {
    int e = blockIdx.x * 256 + threadIdx.x;
    if (e >= E) return;
    int d = dst[e];
    int pos = atomicAdd(&cursor[d], 1);
    eids[offs[d] + pos] = src[e];
}

// ---------- gather + h1: h1 = bf16(relu(y[i] + sum_j y[nbr] + b1)) ----------
__global__ __launch_bounds__(256) void gather_h1_kernel(const float* __restrict__ y,
                                                        const int* __restrict__ offs,
                                                        const int* __restrict__ eids,
                                                        const float* __restrict__ b1,
                                                        unsigned short* __restrict__ h1b,
                                                        int N) {
    int node = blockIdx.x * 2 + (threadIdx.x >> 7);
    if (node >= N) return;
    int c = (threadIdx.x & 127) << 2;
    float4 s = *(const float4*)(y + (size_t)node * 512 + c);
    int beg = offs[node], end = offs[node + 1];
    for (int k = beg; k < end; k++) {
        int sn = eids[k];
        const float4 v = *(const float4*)(y + (size_t)sn * 512 + c);
        s.x += v.x; s.y += v.y; s.z += v.z; s.w += v.w;
    }
    const float4 b = *(const float4*)(b1 + c);
    ushort4 o;
    o.x = f2b(fmaxf(s.x + b.x, 0.f));
    o.y = f2b(fmaxf(s.y + b.y, 0.f));
    o.z = f2b(fmaxf(s.z + b.z, 0.f));
    o.w = f2b(fmaxf(s.w + b.w, 0.f));
    ((ushort4*)h1b)[((size_t)node * 512 + c) >> 2] = o;
}

// =====================================================================
// Swizzled-tile GEMM, 3-slot depth-2 counted-vmcnt pipeline (T3+T4).
// C[M][512] = A[M][KDIM] @ W[KDIM][512]
// Block: 256 thr (4 waves), BM=64 rows, BN=256 cols (cb=blockIdx.y), BK=32.
// LDS 61440B: A slots s*4096 (3x4KB), B slots 12288+s*16384 (3x16KB).
// Loop invariant at iter t: slot sc=t%3 holds tile t (complete);
//   loads for tile t+2 issued this iter; A(t+1) regs (loaded t-1) cvt+written
//   to slot s1 this iter; end wait vmcnt leaves exactly tile-(t+2) loads in
//   flight (AMODE0: 2 A-loads + 4 B-GLDS = 6; AMODE1/2: 5).
// AMODE: 0 = A f32 row-major, 1 = A bf16 row-major, 2 = A pre-tiled (GLDS).
// EPI:   0 = f32 store; 1 = +bias, f32 + pre-tiled bf16 store;
//        2 = alpha[row] += sum tanh(acc+bias)*Wa.
// =====================================================================
template <int KDIM, int AMODE, int EPI>
__global__ __launch_bounds__(256) void gemm_sec(const void* __restrict__ Asrc,
                                                const char* __restrict__ Bpre,
                                                const float* __restrict__ bias,
                                                float* __restrict__ Cf,
                                                char* __restrict__ hbpre,
                                                const float* __restrict__ Wa,
                                                float* __restrict__ alphaOut,
                                                int M) {
    constexpr int NT = KDIM / 32;   // >= 16
    __shared__ char smem[61440];
    const int tid = threadIdx.x, lane = tid & 63, wv = tid >> 6;
    const int fr = lane & 15, sec = lane >> 4, hi4 = (lane >> 4) * 4;
    const long row0 = (long)blockIdx.x * 64;
    const int cb = blockIdx.y;
    const char* Bp = Bpre + (size_t)cb * NT * 16384;

    f32x4 acc[4][4];
#pragma unroll
    for (int m = 0; m < 4; m++)
#pragma unroll
        for (int n = 0; n < 4; n++)
#pragma unroll
            for (int r = 0; r < 4; r++) acc[m][n][r] = 0.f;

    const int as_ = tid & 3, ar_ = tid >> 2;
    const unsigned awz = swz(ar_, as_);
    long arow = row0 + ar_; if (arow > (long)M - 1) arow = M - 1;
    const float* ApF = (const float*)Asrc + arow * KDIM + as_ * 8;       // AMODE 0
    const char*  ApH = (const char*)Asrc + arow * (KDIM * 2) + as_ * 16; // AMODE 1
    const char*  ApT = (const char*)Asrc + (size_t)blockIdx.x * 65536;   // AMODE 2

#define ASEC(s) (smem + (s) * 4096)
#define BSEC(s) (smem + 12288 + (s) * 16384)
#define STAGE_B(s, t) do {                                                \
        const char* src_ = Bp + (size_t)(t) * 16384;                      \
        _Pragma("unroll") for (int c_ = 0; c_ < 4; c_++)                  \
            GLDS(src_ + tid * 16 + c_ * 4096, BSEC(s) + tid * 16 + c_ * 4096); \
    } while (0)

    float4 aP0, aP1, aN0, aN1;   // AMODE 0 staging regs
    u16x8  aPv, aNv;             // AMODE 1 staging regs

    // ---- prologue: tile0 fully staged; tile1 B staged + A in regs ----
    if constexpr (AMODE == 0) {
        aP0 = *(const float4*)(ApF); aP1 = *(const float4*)(ApF + 4);
        STAGE_B(0, 0);
        u16x8 o; o[0]=f2b(aP0.x); o[1]=f2b(aP0.y); o[2]=f2b(aP0.z); o[3]=f2b(aP0.w);
        o[4]=f2b(aP1.x); o[5]=f2b(aP1.y); o[6]=f2b(aP1.z); o[7]=f2b(aP1.w);
        *(u16x8*)(ASEC(0) + awz) = o;
        aP0 = *(const float4*)(ApF + 32); aP1 = *(const float4*)(ApF + 36);
        STAGE_B(1, 1);
        asm volatile("s_waitcnt vmcnt(6) lgkmcnt(0)" ::: "memory");
    } else if constexpr (AMODE == 1) {
        aPv = *(const u16x8*)(ApH);
        STAGE_B(0, 0);
        *(u16x8*)(ASEC(0) + awz) = aPv;
        aPv = *(const u16x8*)(ApH + 64);
        STAGE_B(1, 1);
        asm volatile("s_waitcnt vmcnt(5) lgkmcnt(0)" ::: "memory");
    } else {
        GLDS(ApT + tid * 16, ASEC(0) + tid * 16);
        STAGE_B(0, 0);
        GLDS(ApT + 4096 + tid * 16, ASEC(1) + tid * 16);
        STAGE_B(1, 1);
        asm volatile("s_waitcnt vmcnt(5) lgkmcnt(0)" ::: "memory");
    }
    __builtin_amdgcn_s_barrier();
    __builtin_amdgcn_sched_barrier(0);

    int sc = 0, s1 = 1, s2 = 2;
    for (int t = 0; t < NT; t++) {
        const bool pf = (t + 2 < NT);
        // 1) issue loads for tile t+2 (A first, then B, so cvt's auto-wait
        //    retires only A)
        if (pf) {
            if constexpr (AMODE == 0) {
                aN0 = *(const float4*)(ApF + (t + 2) * 32);
                aN1 = *(const float4*)(ApF + (t + 2) * 32 + 4);
            } else if constexpr (AMODE == 1) {
                aNv = *(const u16x8*)(ApH + (size_t)(t + 2) * 64);
            } else {
                GLDS(ApT + (size_t)(t + 2) * 4096 + tid * 16, ASEC(s2) + tid * 16);
            }
            STAGE_B(s2, t + 2);
        }
        // 2) write A(t+1) into slot s1 (regs loaded last iter)
        if constexpr (AMODE == 0) {
            if (t + 1 < NT) {
                u16x8 o; o[0]=f2b(aP0.x); o[1]=f2b(aP0.y); o[2]=f2b(aP0.z); o[3]=f2b(aP0.w);
                o[4]=f2b(aP1.x); o[5]=f2b(aP1.y); o[6]=f2b(aP1.z); o[7]=f2b(aP1.w);
                *(u16x8*)(ASEC(s1) + awz) = o;
                aP0 = aN0; aP1 = aN1;
            }
        } else if constexpr (AMODE == 1) {
            if (t + 1 < NT) {
                *(u16x8*)(ASEC(s1) + awz) = aPv;
                aPv = aNv;
            }
        }
        // 3) compute tile t from slot sc
        bf16x8 wf[4], xf[4];
#pragma unroll
        for (int m = 0; m < 4; m++)
            wf[m] = *(const bf16x8*)(BSEC(sc) + swz(wv * 64 + m * 16 + fr, sec));
#pragma unroll
        for (int n = 0; n < 4; n++)
            xf[n] = *(const bf16x8*)(ASEC(sc) + swz(n * 16 + fr, sec));
#pragma unroll
        for (int m = 0; m < 4; m++)
#pragma unroll
            for (int n = 0; n < 4; n++)
                acc[m][n] = __builtin_amdgcn_mfma_f32_16x16x32_bf16(wf[m], xf[n], acc[m][n], 0, 0, 0);
        // 4) counted wait + barrier: tile t+1 complete, tile t+2 in flight
        if (t + 1 < NT) {
            if (pf) {
                if constexpr (AMODE == 0)
                    asm volatile("s_waitcnt vmcnt(6) lgkmcnt(0)" ::: "memory");
                else
                    asm volatile("s_waitcnt vmcnt(5) lgkmcnt(0)" ::: "memory");
            } else {
                asm volatile("s_waitcnt vmcnt(0) lgkmcnt(0)" ::: "memory");
            }
            __builtin_amdgcn_s_barrier();
            __builtin_amdgcn_sched_barrier(0);
        }
        int tmp = sc; sc = s1; s1 = s2; s2 = tmp;
    }

    if constexpr (EPI == 0) {
#pragma unroll
        for (int n = 0; n < 4; n++) {
            long node = row0 + n * 16 + fr;
            if (node < M) {
#pragma unroll
                for (int m = 0; m < 4; m++)
                    *(f32x4*)(Cf + node * 512 + cb * 256 + wv * 64 + m * 16 + hi4) = acc[m][n];
            }
        }
    } else if constexpr (EPI == 1) {
#pragma unroll
        for (int n = 0; n < 4; n++) {
            int nodeloc = n * 16 + fr;
            long node = row0 + nodeloc;
#pragma unroll
            for (int m = 0; m < 4; m++) {
                int hc = cb * 256 + wv * 64 + m * 16 + hi4;
                f32x4 bv = *(const f32x4*)(bias + hc);
                f32x4 v = acc[m][n] + bv;
                if (node < M) *(f32x4*)(Cf + node * 512 + hc) = v;
                ushort4 o; o.x = f2b(v[0]); o.y = f2b(v[1]); o.z = f2b(v[2]); o.w = f2b(v[3]);
                int tt = hc >> 5, ss = (hc & 31) >> 3, e = hc & 7;
                *(ushort4*)(hbpre + (size_t)blockIdx.x * 65536 + (size_t)tt * 4096 +
                            swz(nodeloc, ss) + e * 2) = o;
            }
        }
    } else {
        __syncthreads();                   // all waves done reading LDS slots
        float* aS = (float*)smem;
        if (tid < 64) aS[tid] = 0.f;
        __syncthreads();
#pragma unroll
        for (int n = 0; n < 4; n++) {
            float s = 0.f;
#pragma unroll
            for (int m = 0; m < 4; m++) {
                int gc = cb * 256 + wv * 64 + m * 16 + hi4;
                f32x4 bgv = *(const f32x4*)(bias + gc);
                f32x4 wav = *(const f32x4*)(Wa + gc);
#pragma unroll
                for (int r = 0; r < 4; r++)
                    s += tanhf(acc[m][n][r] + bgv[r]) * wav[r];
            }
            atomicAdd(&aS[n * 16 + fr], s);
        }
        __syncthreads();
        if (tid < 64) {
            long node = row0 + tid;
            if (node < M) atomicAdd(&alphaOut[node], aS[tid]);
        }
    }
#undef ASEC
#undef BSEC
#undef STAGE_B
}

// ---------- softmax over 20000 scalars (ba cancels) ----------
__global__ __launch_bounds__(1024) void softmax_kernel(const float* __restrict__ alpha,
                                                       float* __restrict__ att, int N) {
    __shared__ float red[16];
    __shared__ float bc[2];
    int tid = threadIdx.x, lane = tid & 63, wv = tid >> 6;
    float m = -3.4e38f;
    for (int i = tid; i < N; i += 1024) m = fmaxf(m, alpha[i]);
#pragma unroll
    for (int o = 32; o > 0; o >>= 1) m = fmaxf(m, __shfl_xor(m, o, 64));
    if (lane == 0) red[wv] = m;
    __syncthreads();
    if (tid == 0) {
        float mm = red[0];
        for (int i = 1; i < 16; i++) mm = fmaxf(mm, red[i]);
        bc[0] = mm;
    }
    __syncthreads();
    float Mx = bc[0];
    float s = 0.f;
    for (int i = tid; i < N; i += 1024) s += expf(alpha[i] - Mx);
#pragma unroll
    for (int o = 32; o > 0; o >>= 1) s += __shfl_xor(s, o, 64);
    if (lane == 0) red[wv] = s;
    __syncthreads();
    if (tid == 0) {
        float ss = 0.f;
        for (int i = 0; i < 16; i++) ss += red[i];
        bc[1] = ss;
    }
    __syncthreads();
    float inv = 1.f / bc[1];
    for (int i = tid; i < N; i += 1024) att[i] = expf(alpha[i] - Mx) * inv;
}

// ---------- launch ----------
extern "C" void kernel_launch(void* const* d_in, const int* in_sizes, int n_in,
                              void* d_out, int out_size, void* d_ws, size_t ws_size,
                              hipStream_t stream) {
    const float* x  = (const float*)d_in[0];
    const int*   ei = (const int*)d_in[1];     // [2][160000]: src then dst
    const float* W1 = (const float*)d_in[2];
    const float* b1 = (const float*)d_in[3];
    const float* W2 = (const float*)d_in[4];
    const float* b2 = (const float*)d_in[5];
    const float* Wg = (const float*)d_in[6];
    const float* bg = (const float*)d_in[7];
    const float* Wa = (const float*)d_in[8];
    // d_in[9] = ba: cancels in softmax, unused.

    const int M = 20000, IN = 2048, H = 512, E = 160000;

    char* ws = (char*)d_ws;
    float* y      = (float*)ws;                 // 40,960,000
    char*  W1p    = ws + 40960000;              //  2,097,152
    char*  W2p    = ws + 43057152;              //    524,288
    char*  Wgp    = ws + 43581440;              //    524,288
    unsigned short* h1b = (unsigned short*)(ws + 44105728);  // 20,480,000
    char*  hbpre  = ws + 64585728;              // 20,512,768 (313*65536)
    float* alpha  = (float*)(ws + 85098496);    //     80,000
    int*   counts = (int*)(ws + 85178496);      //     80,000
    int*   offs   = (int*)(ws + 85258496);      //     80,004
    int*   cursor = (int*)(ws + 85338504);      //     80,000
    int*   eids   = (int*)(ws + 85418504);      //    640,000

    float* hout = (float*)d_out;                 // [20000][512] f32
    float* att  = hout + (size_t)M * H;          // [20000] f32

    // weights -> pre-tiled + pre-swizzled images (bf16)
    convw_pre_kernel<<<4096, 256, 0, stream>>>(W1, W1p, IN);
    convw_pre_kernel<<<1024, 256, 0, stream>>>(W2, W2p, H);
    convw_pre_kernel<<<1024, 256, 0, stream>>>(Wg, Wgp, H);

    // CSR build by dst
    hipMemsetAsync(counts, 0, M * 4, stream);
    count_kernel<<<(E + 255) / 256, 256, 0, stream>>>(ei + E, counts, E);
    scan_kernel<<<1, 1024, 0, stream>>>(counts, offs, M);
    hipMemsetAsync(cursor, 0, M * 4, stream);
    bucket_kernel<<<(E + 255) / 256, 256, 0, stream>>>(ei, ei + E, offs, cursor, eids, E);

    // y = x @ W1
    gemm_sec<2048, 0, 0><<<dim3(313, 2), 256, 0, stream>>>(x, W1p, nullptr, y, nullptr, nullptr, nullptr, M);

    // h1 = bf16(relu(y_self + gather(y) + b1))
    gather_h1_kernel<<<10000, 256, 0, stream>>>(y, offs, eids, b1, h1b, M);

    // h = h1@W2+b2 -> hout (f32) + hbpre (bf16, pre-tiled+swizzled)
    gemm_sec<512, 1, 1><<<dim3(313, 2), 256, 0, stream>>>(h1b, W2p, b2, hout, hbpre, nullptr, nullptr, M);

    // alpha = rowsum(tanh(h@Wg+bg)*Wa), split over 2 col-blocks via atomics
    hipMemsetAsync(alpha, 0, M * 4, stream);
    gemm_sec<512, 2, 2><<<dim3(313, 2), 256, 0, stream>>>(hbpre, Wgp, bg, nullptr, nullptr, Wa, alpha, M);

    // att = softmax(alpha)
    softmax_kernel<<<1, 1024, 0, stream>>>(alpha, att, M);
}

// Round 7
// 281.258 us; speedup vs baseline: 1.0738x; 1.0738x over previous
//
#include <hip/hip_runtime.h>

// ---------- types ----------
typedef __attribute__((ext_vector_type(8))) __bf16 bf16x8;
typedef __attribute__((ext_vector_type(4))) __bf16 bf16x4;
typedef __attribute__((ext_vector_type(4))) float f32x4;
typedef __attribute__((ext_vector_type(8))) unsigned short u16x8;

// native casts -> compiler emits v_cvt_pk_bf16_f32 (RNE) on gfx950
__device__ __forceinline__ bf16x8 cvt8(float4 a, float4 b) {
    bf16x8 o;
    o[0] = (__bf16)a.x; o[1] = (__bf16)a.y; o[2] = (__bf16)a.z; o[3] = (__bf16)a.w;
    o[4] = (__bf16)b.x; o[5] = (__bf16)b.y; o[6] = (__bf16)b.z; o[7] = (__bf16)b.w;
    return o;
}
__device__ __forceinline__ bf16x4 cvt4(f32x4 v) {
    bf16x4 o;
    o[0] = (__bf16)v[0]; o[1] = (__bf16)v[1]; o[2] = (__bf16)v[2]; o[3] = (__bf16)v[3];
    return o;
}

// m201 st_16x32 swizzle on 64B rows: flips byte-bit5 with row-bit3.
__device__ __forceinline__ unsigned swz(int row, int s) {
    return (unsigned)((row * 64 + s * 16) ^ ((row & 8) << 2));
}

#define GLDS(g, l) __builtin_amdgcn_global_load_lds(                        \
    (const __attribute__((address_space(1))) void*)(g),                     \
    (__attribute__((address_space(3))) void*)(l), 16, 0, 0)

// ---------- W [K][N=512] f32 -> pre-tiled + pre-swizzled bf16 image ----------
__global__ __launch_bounds__(256) void convw_pre_kernel(const float* __restrict__ W,
                                                        char* __restrict__ out, int K) {
    int t = blockIdx.x * 256 + threadIdx.x;
    if (t >= K * 512) return;
    int k = t >> 9, n = t & 511;
    int cb = n >> 8, r = n & 255, tt = k >> 5, s = (k & 31) >> 3, e = k & 7;
    size_t off = ((size_t)cb * (K >> 5) + tt) * 16384 + swz(r, s) + e * 2;
    *(__bf16*)(out + off) = (__bf16)W[t];
}

// ---------- CSR build (by dst) ----------
__global__ __launch_bounds__(256) void count_kernel(const int* __restrict__ dst,
                                                    int* __restrict__ counts, int E) {
    int e = blockIdx.x * 256 + threadIdx.x;
    if (e < E) atomicAdd(&counts[dst[e]], 1);
}

__global__ __launch_bounds__(1024) void scan_kernel(const int* __restrict__ counts,
                                                    int* __restrict__ offs, int N) {
    __shared__ int wsum[16], wpre[16];
    const int CH = 20;
    int tid = threadIdx.x, lane = tid & 63, wv = tid >> 6;
    int base = tid * CH;
    int s = 0;
    for (int i = 0; i < CH; i++) { int idx = base + i; s += (idx < N) ? counts[idx] : 0; }
    int run = s;
#pragma unroll
    for (int o = 1; o < 64; o <<= 1) { int v = __shfl_up(run, o, 64); if (lane >= o) run += v; }
    if (lane == 63) wsum[wv] = run;
    __syncthreads();
    if (tid == 0) { int acc = 0; for (int w = 0; w < 16; w++) { wpre[w] = acc; acc += wsum[w]; } }
    __syncthreads();
    int pre = wpre[wv] + (run - s);
    for (int i = 0; i < CH; i++) {
        int idx = base + i;
        if (idx <= N) offs[idx] = pre;
        pre += (idx < N) ? counts[idx] : 0;
    }
}

__global__ __launch_bounds__(256) void bucket_kernel(const int* __restrict__ src,
                                                     const int* __restrict__ dst,
                                                     const int* __restrict__ offs,
                                                     int* __restrict__ cursor,
                                                     int* __restrict__ eids, int E) {
    int e = blockIdx.x * 256 + threadIdx.x;
    if (e >= E) return;
    int d = dst[e];
    int pos = atomicAdd(&cursor[d], 1);
    eids[offs[d] + pos] = src[e];
}

// ---------- gather + h1: h1 = bf16(relu(y[i] + sum_j y[nbr] + b1)) ----------
__global__ __launch_bounds__(256) void gather_h1_kernel(const float* __restrict__ y,
                                                        const int* __restrict__ offs,
                                                        const int* __restrict__ eids,
                                                        const float* __restrict__ b1,
                                                        __bf16* __restrict__ h1b,
                                                        int N) {
    int node = blockIdx.x * 2 + (threadIdx.x >> 7);
    if (node >= N) return;
    int c = (threadIdx.x & 127) << 2;
    float4 s = *(const float4*)(y + (size_t)node * 512 + c);
    int beg = offs[node], end = offs[node + 1];
    for (int k = beg; k < end; k++) {
        int sn = eids[k];
        const float4 v = *(const float4*)(y + (size_t)sn * 512 + c);
        s.x += v.x; s.y += v.y; s.z += v.z; s.w += v.w;
    }
    const float4 b = *(const float4*)(b1 + c);
    f32x4 r;
    r[0] = fmaxf(s.x + b.x, 0.f);
    r[1] = fmaxf(s.y + b.y, 0.f);
    r[2] = fmaxf(s.z + b.z, 0.f);
    r[3] = fmaxf(s.w + b.w, 0.f);
    *(bf16x4*)(h1b + (size_t)node * 512 + c) = cvt4(r);
}

// =====================================================================
// Swizzled-tile GEMM (R5 2-slot structure, fast cvt):
// C[M][512] = A[M][KDIM] @ W[KDIM][512]
// Block: 256 thr (4 waves), BM=64 rows, BN=256 cols (cb=blockIdx.y), BK=32.
// LDS 40960B: A[2][4KB] @0, B[2][16KB] @8192 — st_16x32-swizzled 64B rows.
// AMODE: 0 = A f32 row-major (cvt_pk in staging), 1 = A bf16 row-major,
//        2 = A pre-tiled+swizzled (linear global_load_lds).
// EPI:   0 = f32 store; 1 = +bias, f32 + pre-tiled bf16 store;
//        2 = alpha[row] += sum tanh(acc+bias)*Wa.
// Swapped MFMA: D = Wfrag*Afrag; node=lane&15, weightcol=(lane>>4)*4+r.
// =====================================================================
template <int KDIM, int AMODE, int EPI>
__global__ __launch_bounds__(256) void gemm_sec(const void* __restrict__ Asrc,
                                                const char* __restrict__ Bpre,
                                                const float* __restrict__ bias,
                                                float* __restrict__ Cf,
                                                char* __restrict__ hbpre,
                                                const float* __restrict__ Wa,
                                                float* __restrict__ alphaOut,
                                                int M) {
    constexpr int NT = KDIM / 32;
    __shared__ char smem[40960];
    const int tid = threadIdx.x, lane = tid & 63, wv = tid >> 6;
    const int fr = lane & 15, sec = lane >> 4, hi4 = (lane >> 4) * 4;
    const long row0 = (long)blockIdx.x * 64;
    const int cb = blockIdx.y;
    const char* Bp = Bpre + (size_t)cb * NT * 16384;

    f32x4 acc[4][4];
#pragma unroll
    for (int m = 0; m < 4; m++)
#pragma unroll
        for (int n = 0; n < 4; n++)
#pragma unroll
            for (int r = 0; r < 4; r++) acc[m][n][r] = 0.f;

    const int as_ = tid & 3, ar_ = tid >> 2;
    const unsigned awz = swz(ar_, as_);
    long arow = row0 + ar_; if (arow > (long)M - 1) arow = M - 1;
    const float* ApF = (const float*)Asrc + arow * KDIM + as_ * 8;       // AMODE 0
    const char*  ApH = (const char*)Asrc + arow * (KDIM * 2) + as_ * 16; // AMODE 1
    const char*  ApT = (const char*)Asrc + (size_t)blockIdx.x * 65536;   // AMODE 2

#define ASEC(b) (smem + (b) * 4096)
#define BSEC(b) (smem + 8192 + (b) * 16384)
#define STAGE_B(buf, t) do {                                              \
        const char* src_ = Bp + (size_t)(t) * 16384;                      \
        _Pragma("unroll") for (int c_ = 0; c_ < 4; c_++)                  \
            GLDS(src_ + tid * 16 + c_ * 4096, BSEC(buf) + tid * 16 + c_ * 4096); \
    } while (0)

    // prologue: stage tile 0 into buf 0
    STAGE_B(0, 0);
    if constexpr (AMODE == 0) {
        float4 a0 = *(const float4*)(ApF), a1 = *(const float4*)(ApF + 4);
        *(bf16x8*)(ASEC(0) + awz) = cvt8(a0, a1);
    } else if constexpr (AMODE == 1) {
        u16x8 v = *(const u16x8*)(ApH);
        *(u16x8*)(ASEC(0) + awz) = v;
    } else {
        GLDS(ApT + tid * 16, ASEC(0) + tid * 16);
    }
    __syncthreads();

    for (int t = 0; t < NT; t++) {
        const int cur = t & 1, nxt = cur ^ 1;
        const bool more = (t + 1 < NT);
        float4 a0, a1; u16x8 av;
        if (more) {
            STAGE_B(nxt, t + 1);
            if constexpr (AMODE == 0) {
                a0 = *(const float4*)(ApF + (t + 1) * 32);
                a1 = *(const float4*)(ApF + (t + 1) * 32 + 4);
            } else if constexpr (AMODE == 1) {
                av = *(const u16x8*)(ApH + (t + 1) * 64);
            } else {
                GLDS(ApT + (size_t)(t + 1) * 4096 + tid * 16, ASEC(nxt) + tid * 16);
            }
        }
        bf16x8 wf[4], xf[4];
#pragma unroll
        for (int m = 0; m < 4; m++)
            wf[m] = *(const bf16x8*)(BSEC(cur) + swz(wv * 64 + m * 16 + fr, sec));
#pragma unroll
        for (int n = 0; n < 4; n++)
            xf[n] = *(const bf16x8*)(ASEC(cur) + swz(n * 16 + fr, sec));
#pragma unroll
        for (int m = 0; m < 4; m++)
#pragma unroll
            for (int n = 0; n < 4; n++)
                acc[m][n] = __builtin_amdgcn_mfma_f32_16x16x32_bf16(wf[m], xf[n], acc[m][n], 0, 0, 0);
        if (more) {
            if constexpr (AMODE == 0) {
                *(bf16x8*)(ASEC(nxt) + awz) = cvt8(a0, a1);
            } else if constexpr (AMODE == 1) {
                *(u16x8*)(ASEC(nxt) + awz) = av;
            }
        }
        __syncthreads();
    }

    if constexpr (EPI == 0) {
#pragma unroll
        for (int n = 0; n < 4; n++) {
            long node = row0 + n * 16 + fr;
            if (node < M) {
#pragma unroll
                for (int m = 0; m < 4; m++)
                    *(f32x4*)(Cf + node * 512 + cb * 256 + wv * 64 + m * 16 + hi4) = acc[m][n];
            }
        }
    } else if constexpr (EPI == 1) {
#pragma unroll
        for (int n = 0; n < 4; n++) {
            int nodeloc = n * 16 + fr;
            long node = row0 + nodeloc;
#pragma unroll
            for (int m = 0; m < 4; m++) {
                int hc = cb * 256 + wv * 64 + m * 16 + hi4;
                f32x4 bv = *(const f32x4*)(bias + hc);
                f32x4 v = acc[m][n] + bv;
                if (node < M) *(f32x4*)(Cf + node * 512 + hc) = v;
                int tt = hc >> 5, ss = (hc & 31) >> 3, e = hc & 7;
                *(bf16x4*)(hbpre + (size_t)blockIdx.x * 65536 + (size_t)tt * 4096 +
                           swz(nodeloc, ss) + e * 2) = cvt4(v);
            }
        }
    } else {
        float* aS = (float*)smem;          // A/B buffers dead after last barrier
        if (tid < 64) aS[tid] = 0.f;
        __syncthreads();
#pragma unroll
        for (int n = 0; n < 4; n++) {
            float s = 0.f;
#pragma unroll
            for (int m = 0; m < 4; m++) {
                int gc = cb * 256 + wv * 64 + m * 16 + hi4;
                f32x4 bgv = *(const f32x4*)(bias + gc);
                f32x4 wav = *(const f32x4*)(Wa + gc);
#pragma unroll
                for (int r = 0; r < 4; r++)
                    s += tanhf(acc[m][n][r] + bgv[r]) * wav[r];
            }
            atomicAdd(&aS[n * 16 + fr], s);
        }
        __syncthreads();
        if (tid < 64) {
            long node = row0 + tid;
            if (node < M) atomicAdd(&alphaOut[node], aS[tid]);
        }
    }
#undef ASEC
#undef BSEC
#undef STAGE_B
}

// ---------- softmax over 20000 scalars (ba cancels) ----------
__global__ __launch_bounds__(1024) void softmax_kernel(const float* __restrict__ alpha,
                                                       float* __restrict__ att, int N) {
    __shared__ float red[16];
    __shared__ float bc[2];
    int tid = threadIdx.x, lane = tid & 63, wv = tid >> 6;
    float m = -3.4e38f;
    for (int i = tid; i < N; i += 1024) m = fmaxf(m, alpha[i]);
#pragma unroll
    for (int o = 32; o > 0; o >>= 1) m = fmaxf(m, __shfl_xor(m, o, 64));
    if (lane == 0) red[wv] = m;
    __syncthreads();
    if (tid == 0) {
        float mm = red[0];
        for (int i = 1; i < 16; i++) mm = fmaxf(mm, red[i]);
        bc[0] = mm;
    }
    __syncthreads();
    float Mx = bc[0];
    float s = 0.f;
    for (int i = tid; i < N; i += 1024) s += expf(alpha[i] - Mx);
#pragma unroll
    for (int o = 32; o > 0; o >>= 1) s += __shfl_xor(s, o, 64);
    if (lane == 0) red[wv] = s;
    __syncthreads();
    if (tid == 0) {
        float ss = 0.f;
        for (int i = 0; i < 16; i++) ss += red[i];
        bc[1] = ss;
    }
    __syncthreads();
    float inv = 1.f / bc[1];
    for (int i = tid; i < N; i += 1024) att[i] = expf(alpha[i] - Mx) * inv;
}

// ---------- launch ----------
extern "C" void kernel_launch(void* const* d_in, const int* in_sizes, int n_in,
                              void* d_out, int out_size, void* d_ws, size_t ws_size,
                              hipStream_t stream) {
    const float* x  = (const float*)d_in[0];
    const int*   ei = (const int*)d_in[1];     // [2][160000]: src then dst
    const float* W1 = (const float*)d_in[2];
    const float* b1 = (const float*)d_in[3];
    const float* W2 = (const float*)d_in[4];
    const float* b2 = (const float*)d_in[5];
    const float* Wg = (const float*)d_in[6];
    const float* bg = (const float*)d_in[7];
    const float* Wa = (const float*)d_in[8];
    // d_in[9] = ba: cancels in softmax, unused.

    const int M = 20000, IN = 2048, H = 512, E = 160000;

    char* ws = (char*)d_ws;
    float* y      = (float*)ws;                 // 40,960,000
    char*  W1p    = ws + 40960000;              //  2,097,152
    char*  W2p    = ws + 43057152;              //    524,288
    char*  Wgp    = ws + 43581440;              //    524,288
    __bf16* h1b   = (__bf16*)(ws + 44105728);   // 20,480,000
    char*  hbpre  = ws + 64585728;              // 20,512,768 (313*65536)
    float* alpha  = (float*)(ws + 85098496);    //     80,000
    int*   counts = (int*)(ws + 85178496);      //     80,000
    int*   offs   = (int*)(ws + 85258496);      //     80,004
    int*   cursor = (int*)(ws + 85338504);      //     80,000
    int*   eids   = (int*)(ws + 85418504);      //    640,000

    float* hout = (float*)d_out;                 // [20000][512] f32
    float* att  = hout + (size_t)M * H;          // [20000] f32

    // weights -> pre-tiled + pre-swizzled images (bf16)
    convw_pre_kernel<<<4096, 256, 0, stream>>>(W1, W1p, IN);
    convw_pre_kernel<<<1024, 256, 0, stream>>>(W2, W2p, H);
    convw_pre_kernel<<<1024, 256, 0, stream>>>(Wg, Wgp, H);

    // CSR build by dst
    hipMemsetAsync(counts, 0, M * 4, stream);
    count_kernel<<<(E + 255) / 256, 256, 0, stream>>>(ei + E, counts, E);
    scan_kernel<<<1, 1024, 0, stream>>>(counts, offs, M);
    hipMemsetAsync(cursor, 0, M * 4, stream);
    bucket_kernel<<<(E + 255) / 256, 256, 0, stream>>>(ei, ei + E, offs, cursor, eids, E);

    // y = x @ W1
    gemm_sec<2048, 0, 0><<<dim3(313, 2), 256, 0, stream>>>(x, W1p, nullptr, y, nullptr, nullptr, nullptr, M);

    // h1 = bf16(relu(y_self + gather(y) + b1))
    gather_h1_kernel<<<10000, 256, 0, stream>>>(y, offs, eids, b1, h1b, M);

    // h = h1@W2+b2 -> hout (f32) + hbpre (bf16, pre-tiled+swizzled)
    gemm_sec<512, 1, 1><<<dim3(313, 2), 256, 0, stream>>>(h1b, W2p, b2, hout, hbpre, nullptr, nullptr, M);

    // alpha = rowsum(tanh(h@Wg+bg)*Wa), split over 2 col-blocks via atomics
    hipMemsetAsync(alpha, 0, M * 4, stream);
    gemm_sec<512, 2, 2><<<dim3(313, 2), 256, 0, stream>>>(hbpre, Wgp, bg, nullptr, nullptr, Wa, alpha, M);

    // att = softmax(alpha)
    softmax_kernel<<<1, 1024, 0, stream>>>(alpha, att, M);
}

// Round 8
// 279.883 us; speedup vs baseline: 1.0791x; 1.0049x over previous
//
#include <hip/hip_runtime.h>

// ---------- types ----------
typedef __attribute__((ext_vector_type(8))) __bf16 bf16x8;
typedef __attribute__((ext_vector_type(4))) __bf16 bf16x4;
typedef __attribute__((ext_vector_type(4))) float f32x4;
typedef __attribute__((ext_vector_type(8))) unsigned short u16x8;

// native casts -> v_cvt_pk_bf16_f32 (RNE) on gfx950
__device__ __forceinline__ bf16x8 cvt8(float4 a, float4 b) {
    bf16x8 o;
    o[0] = (__bf16)a.x; o[1] = (__bf16)a.y; o[2] = (__bf16)a.z; o[3] = (__bf16)a.w;
    o[4] = (__bf16)b.x; o[5] = (__bf16)b.y; o[6] = (__bf16)b.z; o[7] = (__bf16)b.w;
    return o;
}
__device__ __forceinline__ bf16x4 cvt4(f32x4 v) {
    bf16x4 o;
    o[0] = (__bf16)v[0]; o[1] = (__bf16)v[1]; o[2] = (__bf16)v[2]; o[3] = (__bf16)v[3];
    return o;
}

// m201 st_16x32 swizzle on 64B rows: flips byte-bit5 with row-bit3.
__device__ __forceinline__ unsigned swz(int row, int s) {
    return (unsigned)((row * 64 + s * 16) ^ ((row & 8) << 2));
}

// ---------- W [K][N=512] f32 -> pre-tiled + pre-swizzled bf16 image ----------
// tile (cb, tt): cols cb*256..+255 x K tt*32..+31; byte = swz(n&255,(k&31)>>3)+(k&7)*2
__global__ __launch_bounds__(256) void convw_pre_kernel(const float* __restrict__ W,
                                                        char* __restrict__ out, int K) {
    int t = blockIdx.x * 256 + threadIdx.x;
    if (t >= K * 512) return;
    int k = t >> 9, n = t & 511;
    int cb = n >> 8, r = n & 255, tt = k >> 5, s = (k & 31) >> 3, e = k & 7;
    size_t off = ((size_t)cb * (K >> 5) + tt) * 16384 + swz(r, s) + e * 2;
    *(__bf16*)(out + off) = (__bf16)W[t];
}

// ---------- CSR build (by dst) ----------
__global__ __launch_bounds__(256) void count_kernel(const int* __restrict__ dst,
                                                    int* __restrict__ counts, int E) {
    int e = blockIdx.x * 256 + threadIdx.x;
    if (e < E) atomicAdd(&counts[dst[e]], 1);
}

__global__ __launch_bounds__(1024) void scan_kernel(const int* __restrict__ counts,
                                                    int* __restrict__ offs, int N) {
    __shared__ int wsum[16], wpre[16];
    const int CH = 20;
    int tid = threadIdx.x, lane = tid & 63, wv = tid >> 6;
    int base = tid * CH;
    int s = 0;
    for (int i = 0; i < CH; i++) { int idx = base + i; s += (idx < N) ? counts[idx] : 0; }
    int run = s;
#pragma unroll
    for (int o = 1; o < 64; o <<= 1) { int v = __shfl_up(run, o, 64); if (lane >= o) run += v; }
    if (lane == 63) wsum[wv] = run;
    __syncthreads();
    if (tid == 0) { int acc = 0; for (int w = 0; w < 16; w++) { wpre[w] = acc; acc += wsum[w]; } }
    __syncthreads();
    int pre = wpre[wv] + (run - s);
    for (int i = 0; i < CH; i++) {
        int idx = base + i;
        if (idx <= N) offs[idx] = pre;
        pre += (idx < N) ? counts[idx] : 0;
    }
}

__global__ __launch_bounds__(256) void bucket_kernel(const int* __restrict__ src,
                                                     const int* __restrict__ dst,
                                                     const int* __restrict__ offs,
                                                     int* __restrict__ cursor,
                                                     int* __restrict__ eids, int E) {
    int e = blockIdx.x * 256 + threadIdx.x;
    if (e >= E) return;
    int d = dst[e];
    int pos = atomicAdd(&cursor[d], 1);
    eids[offs[d] + pos] = src[e];
}

// ---------- gather + h1: h1 = bf16(relu(y[i] + sum_j y[nbr] + b1)) ----------
__global__ __launch_bounds__(256) void gather_h1_kernel(const float* __restrict__ y,
                                                        const int* __restrict__ offs,
                                                        const int* __restrict__ eids,
                                                        const float* __restrict__ b1,
                                                        __bf16* __restrict__ h1b,
                                                        int N) {
    int node = blockIdx.x * 2 + (threadIdx.x >> 7);
    if (node >= N) return;
    int c = (threadIdx.x & 127) << 2;
    float4 s = *(const float4*)(y + (size_t)node * 512 + c);
    int beg = offs[node], end = offs[node + 1];
    for (int k = beg; k < end; k++) {
        int sn = eids[k];
        const float4 v = *(const float4*)(y + (size_t)sn * 512 + c);
        s.x += v.x; s.y += v.y; s.z += v.z; s.w += v.w;
    }
    const float4 b = *(const float4*)(b1 + c);
    f32x4 r;
    r[0] = fmaxf(s.x + b.x, 0.f);
    r[1] = fmaxf(s.y + b.y, 0.f);
    r[2] = fmaxf(s.z + b.z, 0.f);
    r[3] = fmaxf(s.w + b.w, 0.f);
    *(bf16x4*)(h1b + (size_t)node * 512 + c) = cvt4(r);
}

// =====================================================================
// No-B-staging GEMM: C[M][512] = A[M][KDIM] @ W[KDIM][512]
// 256 thr (4 waves), BM=64, BN=256 (cb=blockIdx.y), A-tile BK=64 (2x32 halves).
// A staged in LDS (4x wave reuse, st_16x32 swizzle, dbuf 2x8KB = 16KB total).
// B-fragments read DIRECTLY from pre-tiled global image (L2-resident, zero
// intra-block reuse -> staging was pure overhead). No global_load_lds =>
// barriers need only lgkmcnt(0) + raw s_barrier (no vmcnt drain).
// AMODE: 0 = A f32 row-major (cvt in staging), 1 = A bf16 row-major.
// EPI:   0 = f32 store; 1 = +bias f32 store; 2 = alpha += sum tanh(acc+b)*Wa.
// Swapped MFMA: D = Wfrag*Afrag; node=lane&15, weightcol=(lane>>4)*4+r.
// =====================================================================
template <int KDIM, int AMODE, int EPI>
__global__ __launch_bounds__(256) void gemm_nb(const void* __restrict__ Asrc,
                                               const char* __restrict__ Bpre,
                                               const float* __restrict__ bias,
                                               float* __restrict__ Cf,
                                               const float* __restrict__ Wa,
                                               float* __restrict__ alphaOut,
                                               int M) {
    constexpr int NT2 = KDIM / 64;
    __shared__ char smem[16384];
    const int tid = threadIdx.x, lane = tid & 63, wv = tid >> 6;
    const int fr = lane & 15, sec = lane >> 4, hi4 = (lane >> 4) * 4;
    const long row0 = (long)blockIdx.x * 64;
    const int cb = blockIdx.y;
    const char* Bp = Bpre + (size_t)cb * (KDIM / 32) * 16384;

    f32x4 acc[4][4];
#pragma unroll
    for (int m = 0; m < 4; m++)
#pragma unroll
        for (int n = 0; n < 4; n++)
#pragma unroll
            for (int r = 0; r < 4; r++) acc[m][n][r] = 0.f;

    // A staging: thread covers row ar_=tid>>2, K-chunks (half h, sec ks)
    const int ar_ = tid >> 2, ks = tid & 3;
    const unsigned awz = swz(ar_, ks);
    long arow = row0 + ar_; if (arow > (long)M - 1) arow = M - 1;
    const float* ApF = (const float*)Asrc + arow * KDIM;          // AMODE 0
    const char*  ApH = (const char*)Asrc + arow * (KDIM * 2);     // AMODE 1

#define ASEC(b) (smem + (b) * 8192)

    // prologue: stage A tile 0 into buf 0
    if constexpr (AMODE == 0) {
        float4 a0 = *(const float4*)(ApF + ks * 8);
        float4 a1 = *(const float4*)(ApF + ks * 8 + 4);
        float4 a2 = *(const float4*)(ApF + 32 + ks * 8);
        float4 a3 = *(const float4*)(ApF + 32 + ks * 8 + 4);
        *(bf16x8*)(ASEC(0) + awz) = cvt8(a0, a1);
        *(bf16x8*)(ASEC(0) + 4096 + awz) = cvt8(a2, a3);
    } else {
        u16x8 v0 = *(const u16x8*)(ApH + ks * 16);
        u16x8 v1 = *(const u16x8*)(ApH + 64 + ks * 16);
        *(u16x8*)(ASEC(0) + awz) = v0;
        *(u16x8*)(ASEC(0) + 4096 + awz) = v1;
    }
    asm volatile("s_waitcnt lgkmcnt(0)" ::: "memory");
    __builtin_amdgcn_s_barrier();

    int cur = 0;
    for (int tt = 0; tt < NT2; tt++) {
        const bool more = (tt + 1 < NT2);
        float4 a0, a1, a2, a3; u16x8 v0, v1;
        if (more) {   // issue next A loads early (hide under compute)
            if constexpr (AMODE == 0) {
                const float* p = ApF + (tt + 1) * 64;
                a0 = *(const float4*)(p + ks * 8);
                a1 = *(const float4*)(p + ks * 8 + 4);
                a2 = *(const float4*)(p + 32 + ks * 8);
                a3 = *(const float4*)(p + 32 + ks * 8 + 4);
            } else {
                const char* p = ApH + (size_t)(tt + 1) * 128;
                v0 = *(const u16x8*)(p + ks * 16);
                v1 = *(const u16x8*)(p + 64 + ks * 16);
            }
        }
#pragma unroll
        for (int h = 0; h < 2; h++) {
            const char* bt = Bp + (size_t)(tt * 2 + h) * 16384;
            bf16x8 wf[4], xf[4];
#pragma unroll
            for (int m = 0; m < 4; m++)
                wf[m] = *(const bf16x8*)(bt + swz(wv * 64 + m * 16 + fr, sec));  // global, L2
#pragma unroll
            for (int n = 0; n < 4; n++)
                xf[n] = *(const bf16x8*)(ASEC(cur) + h * 4096 + swz(n * 16 + fr, sec));
#pragma unroll
            for (int m = 0; m < 4; m++)
#pragma unroll
                for (int n = 0; n < 4; n++)
                    acc[m][n] = __builtin_amdgcn_mfma_f32_16x16x32_bf16(wf[m], xf[n], acc[m][n], 0, 0, 0);
        }
        if (more) {
            const int nxt = cur ^ 1;
            if constexpr (AMODE == 0) {
                *(bf16x8*)(ASEC(nxt) + awz) = cvt8(a0, a1);
                *(bf16x8*)(ASEC(nxt) + 4096 + awz) = cvt8(a2, a3);
            } else {
                *(u16x8*)(ASEC(nxt) + awz) = v0;
                *(u16x8*)(ASEC(nxt) + 4096 + awz) = v1;
            }
            asm volatile("s_waitcnt lgkmcnt(0)" ::: "memory");
            __builtin_amdgcn_s_barrier();
            cur = nxt;
        }
    }

    if constexpr (EPI == 0) {
#pragma unroll
        for (int n = 0; n < 4; n++) {
            long node = row0 + n * 16 + fr;
            if (node < M) {
#pragma unroll
                for (int m = 0; m < 4; m++)
                    *(f32x4*)(Cf + node * 512 + cb * 256 + wv * 64 + m * 16 + hi4) = acc[m][n];
            }
        }
    } else if constexpr (EPI == 1) {
#pragma unroll
        for (int n = 0; n < 4; n++) {
            long node = row0 + n * 16 + fr;
            if (node < M) {
#pragma unroll
                for (int m = 0; m < 4; m++) {
                    int hc = cb * 256 + wv * 64 + m * 16 + hi4;
                    f32x4 bv = *(const f32x4*)(bias + hc);
                    *(f32x4*)(Cf + node * 512 + hc) = acc[m][n] + bv;
                }
            }
        }
    } else {
        __syncthreads();                    // all waves done with LDS
        float* aS = (float*)smem;
        if (tid < 64) aS[tid] = 0.f;
        __syncthreads();
#pragma unroll
        for (int n = 0; n < 4; n++) {
            float s = 0.f;
#pragma unroll
            for (int m = 0; m < 4; m++) {
                int gc = cb * 256 + wv * 64 + m * 16 + hi4;
                f32x4 bgv = *(const f32x4*)(bias + gc);
                f32x4 wav = *(const f32x4*)(Wa + gc);
#pragma unroll
                for (int r = 0; r < 4; r++)
                    s += tanhf(acc[m][n][r] + bgv[r]) * wav[r];
            }
            atomicAdd(&aS[n * 16 + fr], s);
        }
        __syncthreads();
        if (tid < 64) {
            long node = row0 + tid;
            if (node < M) atomicAdd(&alphaOut[node], aS[tid]);
        }
    }
#undef ASEC
}

// ---------- softmax over 20000 scalars (ba cancels) ----------
__global__ __launch_bounds__(1024) void softmax_kernel(const float* __restrict__ alpha,
                                                       float* __restrict__ att, int N) {
    __shared__ float red[16];
    __shared__ float bc[2];
    int tid = threadIdx.x, lane = tid & 63, wv = tid >> 6;
    float m = -3.4e38f;
    for (int i = tid; i < N; i += 1024) m = fmaxf(m, alpha[i]);
#pragma unroll
    for (int o = 32; o > 0; o >>= 1) m = fmaxf(m, __shfl_xor(m, o, 64));
    if (lane == 0) red[wv] = m;
    __syncthreads();
    if (tid == 0) {
        float mm = red[0];
        for (int i = 1; i < 16; i++) mm = fmaxf(mm, red[i]);
        bc[0] = mm;
    }
    __syncthreads();
    float Mx = bc[0];
    float s = 0.f;
    for (int i = tid; i < N; i += 1024) s += expf(alpha[i] - Mx);
#pragma unroll
    for (int o = 32; o > 0; o >>= 1) s += __shfl_xor(s, o, 64);
    if (lane == 0) red[wv] = s;
    __syncthreads();
    if (tid == 0) {
        float ss = 0.f;
        for (int i = 0; i < 16; i++) ss += red[i];
        bc[1] = ss;
    }
    __syncthreads();
    float inv = 1.f / bc[1];
    for (int i = tid; i < N; i += 1024) att[i] = expf(alpha[i] - Mx) * inv;
}

// ---------- launch ----------
extern "C" void kernel_launch(void* const* d_in, const int* in_sizes, int n_in,
                              void* d_out, int out_size, void* d_ws, size_t ws_size,
                              hipStream_t stream) {
    const float* x  = (const float*)d_in[0];
    const int*   ei = (const int*)d_in[1];     // [2][160000]: src then dst
    const float* W1 = (const float*)d_in[2];
    const float* b1 = (const float*)d_in[3];
    const float* W2 = (const float*)d_in[4];
    const float* b2 = (const float*)d_in[5];
    const float* Wg = (const float*)d_in[6];
    const float* bg = (const float*)d_in[7];
    const float* Wa = (const float*)d_in[8];
    // d_in[9] = ba: cancels in softmax, unused.

    const int M = 20000, IN = 2048, H = 512, E = 160000;

    char* ws = (char*)d_ws;
    float* y      = (float*)ws;                 // 40,960,000
    char*  W1p    = ws + 40960000;              //  2,097,152
    char*  W2p    = ws + 43057152;              //    524,288
    char*  Wgp    = ws + 43581440;              //    524,288
    __bf16* h1b   = (__bf16*)(ws + 44105728);   // 20,480,000
    float* alpha  = (float*)(ws + 64585728);    //     80,000
    int*   counts = (int*)(ws + 64665728);      //     80,000
    int*   offs   = (int*)(ws + 64745728);      //     80,004
    int*   cursor = (int*)(ws + 64825732);      //     80,000
    int*   eids   = (int*)(ws + 64905732);      //    640,000

    float* hout = (float*)d_out;                 // [20000][512] f32
    float* att  = hout + (size_t)M * H;          // [20000] f32

    // weights -> pre-tiled + pre-swizzled images (bf16)
    convw_pre_kernel<<<4096, 256, 0, stream>>>(W1, W1p, IN);
    convw_pre_kernel<<<1024, 256, 0, stream>>>(W2, W2p, H);
    convw_pre_kernel<<<1024, 256, 0, stream>>>(Wg, Wgp, H);

    // CSR build by dst
    hipMemsetAsync(counts, 0, M * 4, stream);
    count_kernel<<<(E + 255) / 256, 256, 0, stream>>>(ei + E, counts, E);
    scan_kernel<<<1, 1024, 0, stream>>>(counts, offs, M);
    hipMemsetAsync(cursor, 0, M * 4, stream);
    bucket_kernel<<<(E + 255) / 256, 256, 0, stream>>>(ei, ei + E, offs, cursor, eids, E);

    // y = x @ W1  (A f32 cvt in staging; B direct from L2)
    gemm_nb<2048, 0, 0><<<dim3(313, 2), 256, 0, stream>>>(x, W1p, nullptr, y, nullptr, nullptr, M);

    // h1 = bf16(relu(y_self + gather(y) + b1))
    gather_h1_kernel<<<10000, 256, 0, stream>>>(y, offs, eids, b1, h1b, M);

    // h = h1@W2+b2 -> d_out (f32 only; gemm3 re-reads it)
    gemm_nb<512, 1, 1><<<dim3(313, 2), 256, 0, stream>>>(h1b, W2p, b2, hout, nullptr, nullptr, M);

    // alpha = rowsum(tanh(h@Wg+bg)*Wa)  (A = hout f32, cvt in staging)
    hipMemsetAsync(alpha, 0, M * 4, stream);
    gemm_nb<512, 0, 2><<<dim3(313, 2), 256, 0, stream>>>(hout, Wgp, bg, nullptr, Wa, alpha, M);

    // att = softmax(alpha)
    softmax_kernel<<<1, 1024, 0, stream>>>(alpha, att, M);
}